// Round 16
// baseline (59.114 us; speedup 1.0000x reference)
//
#include <hip/hip_runtime.h>

#define B 32
#define M 32
#define H 128
#define EPS 1e-6f
#define TSCALE 2.8853900817779268f   // 2*log2(e)

typedef float v2f __attribute__((ext_vector_type(2)));
typedef float v4f __attribute__((ext_vector_type(4)));

static __device__ __forceinline__ v2f splat2(float x) { return (v2f){x, x}; }
static __device__ __forceinline__ v4f splat4(float x) { return (v4f){x, x, x, x}; }
static __device__ __forceinline__ v2f fma2(v2f a, v2f b, v2f c) {
    return __builtin_elementwise_fma(a, b, c);
}
static __device__ __forceinline__ v4f fma4(v4f a, v4f b, v4f c) {
    return __builtin_elementwise_fma(a, b, c);
}

// ---------------- workspace layout (floats) ----------------
// metric  @ 0      : 32768
// mj      @ 32768  : 262144  mj[b][j][d]  = metric[b,j,:] @ Wr1[64:96]
// S       @ 294912 : 8192
// bc1s    @ 303104 : 128     bc1 * 2log2(e)
// Kc      @ 303232 : 1       sum(Wc2) + bc2
// cnt     @ 303236 : 32 ints
// Wp      @ 303268 : 262144  Wp[u][b][i] = sum_j sym(Wr2)[u,i,j] * p[b,j]
// c2      @ 565412 : 1024    c2[b][i]    = sum_j sym(br2)[i,j] * p[b,j]
// bmi_pre @ 566436 : 262144  bmi_pre[b][i][d] = br1 + p@Wr1[0:32] + metric_i@Wr1[32:64]

#define FMA4(P, s, W) \
    P.x = fmaf((s), (W).x, P.x); P.y = fmaf((s), (W).y, P.y); \
    P.z = fmaf((s), (W).z, P.z); P.w = fmaf((s), (W).w, P.w);

// Kernel 1, grid 289: blocks 0-31 = per-b prep (metric, mj, bmi_pre, zero
// S/cnt, chris constants); blocks 32-287 = Wp row u = blk-32; block 288 = c2.
__global__ __launch_bounds__(256) void k_prep(
    const float* __restrict__ points, const float* __restrict__ Wm1,
    const float* __restrict__ bm1, const float* __restrict__ Wm2,
    const float* __restrict__ bm2, const float* __restrict__ Wr1,
    const float* __restrict__ br1, const float* __restrict__ bc1,
    const float* __restrict__ Wc2, const float* __restrict__ bc2,
    const float* __restrict__ Wr2, const float* __restrict__ br2,
    float* __restrict__ metric, float* __restrict__ mj,
    float* __restrict__ S, float* __restrict__ bc1s, float* __restrict__ Kc,
    int* __restrict__ cnt, float* __restrict__ Wp, float* __restrict__ c2,
    float* __restrict__ bmi_pre)
{
    __shared__ float sbuf[3392];
    const int role = blockIdx.x, t = threadIdx.x;

    if (role >= B) {
        // ---- Wp / c2 path: symmetrize one Wr2 row, contract with points ----
        const int u = role - B;                 // 0..255 = Wr2 row, 256 = br2
        float* row    = sbuf;                   // [32][33] = 1056
        float* rowsym = sbuf + 1056;            // [32][36] = 1152
        float* ps     = sbuf + 2208;            // [32][36] = 1152
        const float* src = (u < 256) ? (Wr2 + u * 1024) : br2;
        #pragma unroll
        for (int r = 0; r < 4; ++r) {
            const int d = t + 256 * r;
            row[(d >> 5) * 33 + (d & 31)] = src[d];
            ps[(d >> 5) * 36 + (d & 31)]  = points[d];
        }
        __syncthreads();
        #pragma unroll
        for (int r = 0; r < 4; ++r) {
            const int d = t + 256 * r, ii = d >> 5, jj = d & 31;
            rowsym[ii * 36 + jj] = 0.5f * (row[ii * 33 + jj] + row[jj * 33 + ii]);
        }
        __syncthreads();
        const int b = t >> 3, i0 = (t & 7) * 4;
        const float4* rs4 = (const float4*)rowsym;      // row stride 9 float4
        const float4* p4  = (const float4*)(ps + b * 36);
        float4 o; o.x = o.y = o.z = o.w = 0.f;
        #pragma unroll
        for (int m = 0; m < 8; ++m) {
            const float4 pv = p4[m];
            const float4 r0 = rs4[(i0 + 0) * 9 + m];
            const float4 r1 = rs4[(i0 + 1) * 9 + m];
            const float4 r2 = rs4[(i0 + 2) * 9 + m];
            const float4 r3 = rs4[(i0 + 3) * 9 + m];
            o.x = fmaf(pv.x, r0.x, fmaf(pv.y, r0.y, fmaf(pv.z, r0.z, fmaf(pv.w, r0.w, o.x))));
            o.y = fmaf(pv.x, r1.x, fmaf(pv.y, r1.y, fmaf(pv.z, r1.z, fmaf(pv.w, r1.w, o.y))));
            o.z = fmaf(pv.x, r2.x, fmaf(pv.y, r2.y, fmaf(pv.z, r2.z, fmaf(pv.w, r2.w, o.z))));
            o.w = fmaf(pv.x, r3.x, fmaf(pv.y, r3.y, fmaf(pv.z, r3.z, fmaf(pv.w, r3.w, o.w))));
        }
        if (u < 256) ((float4*)(Wp + u * 1024 + b * 32))[t & 7] = o;
        else         ((float4*)(c2 + b * 32))[t & 7] = o;
        return;
    }

    // ---- per-b prep path ----
    const int b = role;
    float* p     = sbuf;           // 32
    float* h     = sbuf + 32;      // 128
    float* comps = sbuf + 160;     // [32][33] = 1056
    float* msym  = sbuf + 1216;    // 1024
    if (t < M) p[t] = points[b * M + t];
    __syncthreads();
    if (t < H) {
        float acc = bm1[t];
        #pragma unroll
        for (int m = 0; m < M; ++m) acc = fmaf(p[m], Wm1[m * H + t], acc);
        h[t] = fmaxf(acc, 0.f);
    }
    __syncthreads();
    // comps: thread t owns 4 consecutive dims; b128 Wm2 loads, h broadcasts.
    {
        float4 acc = ((const float4*)bm2)[t];
        const float4* Wm2_4 = (const float4*)Wm2;     // row stride 256 float4
        const float4* h4 = (const float4*)h;
        #pragma unroll 2
        for (int u4 = 0; u4 < 32; ++u4) {
            const float4 hv = h4[u4];
            const float4 w0 = Wm2_4[(u4 * 4 + 0) * 256 + t];
            const float4 w1 = Wm2_4[(u4 * 4 + 1) * 256 + t];
            const float4 w2 = Wm2_4[(u4 * 4 + 2) * 256 + t];
            const float4 w3 = Wm2_4[(u4 * 4 + 3) * 256 + t];
            FMA4(acc, hv.x, w0); FMA4(acc, hv.y, w1);
            FMA4(acc, hv.z, w2); FMA4(acc, hv.w, w3);
        }
        const int row = t >> 3, col0 = (t & 7) * 4;
        comps[row * 33 + col0 + 0] = acc.x;
        comps[row * 33 + col0 + 1] = acc.y;
        comps[row * 33 + col0 + 2] = acc.z;
        comps[row * 33 + col0 + 3] = acc.w;
    }
    __syncthreads();
    {
        const int row = t >> 3, col0 = (t & 7) * 4;
        #pragma unroll
        for (int c = 0; c < 4; ++c) {
            const int d = 4 * t + c, ii = row, jj = col0 + c;
            float v = 0.5f * (comps[ii * 33 + jj] + comps[jj * 33 + ii]) + (ii == jj ? EPS : 0.f);
            metric[b * M * M + d] = v;
            msym[d] = v;
        }
    }
    S[b * 256 + t] = 0.f;
    if (t == 0) cnt[b] = 0;
    __syncthreads();
    // mj[b][x][t] and bmi_pre[b][x][t] in one pass (wreg = Wr1[64:96],
    // wreg2 = Wr1[32:64]); pbr = br1 + points@Wr1[0:32].
    float wreg[M], wreg2[M];
    #pragma unroll
    for (int m = 0; m < M; ++m) {
        wreg[m]  = Wr1[(64 + m) * 256 + t];
        wreg2[m] = Wr1[(32 + m) * 256 + t];
    }
    float pbr = br1[t];
    #pragma unroll
    for (int m = 0; m < M; ++m) pbr = fmaf(p[m], Wr1[m * 256 + t], pbr);
    const float4* msym4 = (const float4*)msym;   // broadcast reads
    for (int x = 0; x < M; ++x) {
        float acc = 0.f, acc2 = pbr;
        #pragma unroll
        for (int mq = 0; mq < 8; ++mq) {
            float4 mv = msym4[x * 8 + mq];
            acc  = fmaf(mv.x, wreg[4 * mq + 0], acc);
            acc  = fmaf(mv.y, wreg[4 * mq + 1], acc);
            acc  = fmaf(mv.z, wreg[4 * mq + 2], acc);
            acc  = fmaf(mv.w, wreg[4 * mq + 3], acc);
            acc2 = fmaf(mv.x, wreg2[4 * mq + 0], acc2);
            acc2 = fmaf(mv.y, wreg2[4 * mq + 1], acc2);
            acc2 = fmaf(mv.z, wreg2[4 * mq + 2], acc2);
            acc2 = fmaf(mv.w, wreg2[4 * mq + 3], acc2);
        }
        mj[(b * M + x) * 256 + t] = acc;
        bmi_pre[(b * M + x) * 256 + t] = acc2;
    }
    if (b == 0) {
        if (t < H) bc1s[t] = bc1[t] * TSCALE;
        if (t == 0) {
            float s = bc2[0];
            for (int u = 0; u < H; ++u) s += Wc2[u];
            Kc[0] = s;
        }
    }
}

// Kernel 2, grid 512: block (b, i-pair {2g, 2g+1}). Each lane runs TWO
// independent v2f chris streams (4 tanh evals in flight — hides the
// ~30-cycle trans dependent chain that pinned VALUBusy at ~57%), sharing
// the gjk*W + bias term. Ricci reuses each weight load for 8 accumulators.
// 16th finisher per b runs the tiny Wp epilogue.
__global__ __launch_bounds__(512) void k_main(
    const float* __restrict__ points, const float* __restrict__ metric,
    const float* __restrict__ mj, const float* __restrict__ bmi_pre,
    const float* __restrict__ Wc1, const float* __restrict__ Wc2,
    const float* __restrict__ bc1s, const float* __restrict__ Kc,
    const float* __restrict__ Wr1, float* __restrict__ S,
    int* __restrict__ cnt,
    const float* __restrict__ Wp, const float* __restrict__ c2,
    const float* __restrict__ Wf1, const float* __restrict__ bf1,
    const float* __restrict__ Wf2, const float* __restrict__ bf2,
    const float* __restrict__ Wh1, const float* __restrict__ bh1,
    const float* __restrict__ Wh2, const float* __restrict__ bh2,
    float* __restrict__ out)
{
    const int blk = blockIdx.x;
    const int b = blk & 31, g = blk >> 5;      // same-b blocks share an XCD
    const int i0 = 2 * g, i1 = 2 * g + 1;
    const int t = threadIdx.x;
    const int w = t >> 6, l = t & 63;
    const int ph = l >> 5, k = l & 31;

    __shared__ float chlds[8 * 256];  // per-wave chris [i][k][slot] (8 KB)
    __shared__ float Slds[256];       // 1 KB
    __shared__ int finflag;

    // ---- early loads ----
    const float* mb = metric + b * 1024;
    const int j0 = 2 * w + ph, j1 = 16 + 2 * w + ph;
    const float gki0 = mb[i0 * M + k] * TSCALE;
    const float gki1 = mb[i1 * M + k] * TSCALE;
    const v2f gij0v = {mb[i0 * M + j0] * TSCALE, mb[i0 * M + j1] * TSCALE};
    const v2f gij1v = {mb[i1 * M + j0] * TSCALE, mb[i1 * M + j1] * TSCALE};
    const v2f gjkv  = {mb[j0 * M + k] * TSCALE, mb[j1 * M + k] * TSCALE};
    const v4f* mj4 = (const v4f*)(mj + b * M * 256);
    const int jb = w * 2;
    const v4f m0 = mj4[(jb + 0) * 64 + l];
    const v4f m1 = mj4[(jb + 1) * 64 + l];
    const v4f m2 = mj4[(jb + 16) * 64 + l];
    const v4f m3 = mj4[(jb + 17) * 64 + l];
    const v4f bmiv0 = ((const v4f*)(bmi_pre + (b * M + i0) * 256))[l];
    const v4f bmiv1 = ((const v4f*)(bmi_pre + (b * M + i1) * 256))[l];
    if (t < 256) Slds[t] = 0.f;

    // ---- christoffel: 2 i's x v2f = 4 independent tanh streams ----
    v2f accA = {0.f, 0.f}, accB = {0.f, 0.f};
    #pragma unroll 4
    for (int u = 0; u < H; ++u) {
        const float w1u = Wc1[u], w2u = Wc1[H + u], w3u = Wc1[2 * H + u];
        const float c2u = Wc2[u];
        const v2f base = fma2(gjkv, splat2(w2u), splat2(bc1s[u]));  // shared
        v2f pre0 = fma2(gij0v, splat2(w1u), fma2(splat2(gki0), splat2(w3u), base));
        v2f pre1 = fma2(gij1v, splat2(w1u), fma2(splat2(gki1), splat2(w3u), base));
        v2f e0 = {__builtin_amdgcn_exp2f(pre0.x), __builtin_amdgcn_exp2f(pre0.y)};
        v2f e1 = {__builtin_amdgcn_exp2f(pre1.x), __builtin_amdgcn_exp2f(pre1.y)};
        e0 += (v2f){1.f, 1.f};
        e1 += (v2f){1.f, 1.f};
        const v2f r0 = {__builtin_amdgcn_rcpf(e0.x), __builtin_amdgcn_rcpf(e0.y)};
        const v2f r1 = {__builtin_amdgcn_rcpf(e1.x), __builtin_amdgcn_rcpf(e1.y)};
        accA = fma2(r0, splat2(c2u), accA);
        accB = fma2(r1, splat2(c2u), accB);
    }
    const float KcV = Kc[0];
    // per-wave scratch, packed [i][k][slot] -> two broadcast b128 per k.
    float* chw = chlds + w * 256;
    chw[k * 4 + ph]           = fmaf(-2.f, accA.x, KcV);   // i0, j0-group
    chw[k * 4 + 2 + ph]       = fmaf(-2.f, accA.y, KcV);   // i0, j1-group
    chw[128 + k * 4 + ph]     = fmaf(-2.f, accB.x, KcV);   // i1, j0-group
    chw[128 + k * 4 + 2 + ph] = fmaf(-2.f, accB.y, KcV);   // i1, j1-group
    // wave-private: intra-wave lgkmcnt ordering suffices, no barrier.

    // ---- ricci layer-1: one weight load feeds 8 accumulators ----
    const v4f* wg = (const v4f*)(Wr1 + 96 * 256);
    const v4f* chA = (const v4f*)chw;          // i0 broadcasts
    const v4f* chB = chA + 32;                 // i1 broadcasts
    v4f a0 = m0 + bmiv0, a1 = m1 + bmiv0, a2 = m2 + bmiv0, a3 = m3 + bmiv0;
    v4f b0 = m0 + bmiv1, b1 = m1 + bmiv1, b2 = m2 + bmiv1, b3 = m3 + bmiv1;

    #define STEP(W, kk) { \
        const v4f sA = chA[kk]; const v4f sB = chB[kk]; \
        a0 = fma4(splat4(sA.x), W, a0); a1 = fma4(splat4(sA.y), W, a1); \
        a2 = fma4(splat4(sA.z), W, a2); a3 = fma4(splat4(sA.w), W, a3); \
        b0 = fma4(splat4(sB.x), W, b0); b1 = fma4(splat4(sB.y), W, b1); \
        b2 = fma4(splat4(sB.z), W, b2); b3 = fma4(splat4(sB.w), W, b3); }

    #pragma unroll
    for (int kc = 0; kc < 8; ++kc) {
        const int kb = kc * 4;
        const v4f w0 = wg[(kb + 0) * 64 + l];
        const v4f w1 = wg[(kb + 1) * 64 + l];
        const v4f w2 = wg[(kb + 2) * 64 + l];
        const v4f w3 = wg[(kb + 3) * 64 + l];
        STEP(w0, kb + 0) STEP(w1, kb + 1) STEP(w2, kb + 2) STEP(w3, kb + 3)
    }
    #undef STEP

    const v4f z4 = {0.f, 0.f, 0.f, 0.f};
    v4f rs = __builtin_elementwise_max(a0, z4) + __builtin_elementwise_max(a1, z4)
           + __builtin_elementwise_max(a2, z4) + __builtin_elementwise_max(a3, z4)
           + __builtin_elementwise_max(b0, z4) + __builtin_elementwise_max(b1, z4)
           + __builtin_elementwise_max(b2, z4) + __builtin_elementwise_max(b3, z4);
    atomicAdd(&Slds[4*l + 0], rs.x);
    atomicAdd(&Slds[4*l + 1], rs.y);
    atomicAdd(&Slds[4*l + 2], rs.z);
    atomicAdd(&Slds[4*l + 3], rs.w);
    __syncthreads();
    if (t < 256) atomicAdd(&S[b * 256 + t], Slds[t]);
    asm volatile("s_waitcnt vmcnt(0)" ::: "memory");  // S atomics done before cnt
    __syncthreads();
    if (t == 0) {
        int old = atomicAdd(&cnt[b], 1);
        finflag = (old == 15);
    }
    __syncthreads();
    if (!finflag) return;

    // ===== tiny epilogue (one block per b): ricci_dir via Wp, then MLPs =====
    float* fs   = chlds;          // 256
    float* rdp  = chlds + 256;    // 512
    float* pl   = chlds + 768;    // 32
    float* fin  = chlds + 800;    // 64
    float* hf   = chlds + 864;    // 128
    float* npos = Slds;           // 32
    float* hh   = Slds + 32;      // 128

    if (t < 256) fs[t] = atomicAdd(&S[b * 256 + t], 0.f) * (1.f / 1024.f);
    if (t < M) pl[t] = points[b * M + t];
    __syncthreads();
    {
        const int ii = t & 31, ch = t >> 5;   // 16 chunks x 16 u's
        float part = 0.f;
        #pragma unroll
        for (int uu = 0; uu < 16; ++uu) {
            const int u = ch * 16 + uu;
            part = fmaf(fs[u], Wp[u * 1024 + b * 32 + ii], part);
        }
        rdp[t] = part;
    }
    __syncthreads();
    if (t < M) {
        float a = c2[b * 32 + t];
        #pragma unroll
        for (int ch = 0; ch < 16; ++ch) a += rdp[ch * 32 + t];
        fin[t] = pl[t];
        fin[M + t] = a;
    }
    __syncthreads();
    if (t < H) {
        float acc = bf1[t];
        #pragma unroll
        for (int m = 0; m < 2 * M; ++m) acc = fmaf(fin[m], Wf1[m * H + t], acc);
        hf[t] = fmaxf(acc, 0.f);
    }
    __syncthreads();
    if (t < M) {
        float acc = bf2[t];
        #pragma unroll
        for (int u = 0; u < H; ++u) acc = fmaf(hf[u], Wf2[u * M + t], acc);
        npos[t] = pl[t] + acc;
    }
    __syncthreads();
    if (t < H) {
        float acc = bh1[t];
        #pragma unroll
        for (int m = 0; m < M; ++m) acc = fmaf(npos[m], Wh1[m * H + t], acc);
        hh[t] = tanhf(acc);
    }
    __syncthreads();
    if (t < 2 * M) {
        float acc = bh2[t];
        #pragma unroll
        for (int u = 0; u < H; ++u) acc = fmaf(hh[u], Wh2[u * (2 * M) + t], acc);
        out[b * (2 * M) + t] = acc;
    }
}

extern "C" void kernel_launch(void* const* d_in, const int* in_sizes, int n_in,
                              void* d_out, int out_size, void* d_ws, size_t ws_size,
                              hipStream_t stream)
{
    const float* points = (const float*)d_in[0];
    const float* Wm1 = (const float*)d_in[1];
    const float* bm1 = (const float*)d_in[2];
    const float* Wm2 = (const float*)d_in[3];
    const float* bm2 = (const float*)d_in[4];
    const float* Wc1 = (const float*)d_in[5];
    const float* bc1 = (const float*)d_in[6];
    const float* Wc2 = (const float*)d_in[7];
    const float* bc2 = (const float*)d_in[8];
    const float* Wr1 = (const float*)d_in[9];
    const float* br1 = (const float*)d_in[10];
    const float* Wr2 = (const float*)d_in[11];
    const float* br2 = (const float*)d_in[12];
    const float* Wf1 = (const float*)d_in[13];
    const float* bf1 = (const float*)d_in[14];
    const float* Wf2 = (const float*)d_in[15];
    const float* bf2 = (const float*)d_in[16];
    const float* Wh1 = (const float*)d_in[17];
    const float* bh1 = (const float*)d_in[18];
    const float* Wh2 = (const float*)d_in[19];
    const float* bh2 = (const float*)d_in[20];
    float* out = (float*)d_out;

    float* ws      = (float*)d_ws;
    float* metric  = ws;                    // 32768
    float* mj      = ws + 32768;            // 262144
    float* S       = ws + 294912;           // 8192
    float* bc1s    = ws + 303104;           // 128
    float* Kc      = ws + 303232;           // 1
    int*   cnt     = (int*)(ws + 303236);   // 32 ints
    float* Wp      = ws + 303268;           // 262144
    float* c2      = ws + 565412;           // 1024
    float* bmi_pre = ws + 566436;           // 262144

    k_prep<<<289, 256, 0, stream>>>(points, Wm1, bm1, Wm2, bm2, Wr1, br1, bc1,
                                    Wc2, bc2, Wr2, br2, metric, mj, S, bc1s,
                                    Kc, cnt, Wp, c2, bmi_pre);
    k_main<<<B * 16, 512, 0, stream>>>(points, metric, mj, bmi_pre, Wc1, Wc2,
                                       bc1s, Kc, Wr1, S, cnt,
                                       Wp, c2, Wf1, bf1, Wf2, bf2,
                                       Wh1, bh1, Wh2, bh2, out);
}

// Round 17
// 56.488 us; speedup vs baseline: 1.0465x; 1.0465x over previous
//
#include <hip/hip_runtime.h>

#define B 32
#define M 32
#define H 128
#define EPS 1e-6f
#define TSCALE 2.8853900817779268f   // 2*log2(e)

typedef float v2f __attribute__((ext_vector_type(2)));
typedef float v4f __attribute__((ext_vector_type(4)));

static __device__ __forceinline__ v2f splat2(float x) { return (v2f){x, x}; }
static __device__ __forceinline__ v4f splat4(float x) { return (v4f){x, x, x, x}; }
static __device__ __forceinline__ v2f fma2(v2f a, v2f b, v2f c) {
    return __builtin_elementwise_fma(a, b, c);
}
static __device__ __forceinline__ v4f fma4(v4f a, v4f b, v4f c) {
    return __builtin_elementwise_fma(a, b, c);
}

// ---------------- workspace layout (floats) ----------------
// metric  @ 0      : 32768
// mj      @ 32768  : 262144  mj[b][j][d]  = metric[b,j,:] @ Wr1[64:96]
// S       @ 294912 : 8192
// bc1s    @ 303104 : 128     bc1 * 2log2(e)
// Kc      @ 303232 : 1       sum(Wc2) + bc2
// cnt     @ 303236 : 32 ints
// Wp      @ 303268 : 262144  Wp[u][b][i] = sum_j sym(Wr2)[u,i,j] * p[b,j]
// c2      @ 565412 : 1024    c2[b][i]    = sum_j sym(br2)[i,j] * p[b,j]
// bmi_pre @ 566436 : 262144  bmi_pre[b][i][d] = br1 + p@Wr1[0:32] + metric_i@Wr1[32:64]

#define FMA4(P, s, W) \
    P.x = fmaf((s), (W).x, P.x); P.y = fmaf((s), (W).y, P.y); \
    P.z = fmaf((s), (W).z, P.z); P.w = fmaf((s), (W).w, P.w);

// Kernel 1, grid 289: blocks 0-31 = per-b prep (metric, mj, bmi_pre, zero
// S/cnt, chris constants); blocks 32-287 = Wp row u = blk-32; block 288 = c2.
__global__ __launch_bounds__(256) void k_prep(
    const float* __restrict__ points, const float* __restrict__ Wm1,
    const float* __restrict__ bm1, const float* __restrict__ Wm2,
    const float* __restrict__ bm2, const float* __restrict__ Wr1,
    const float* __restrict__ br1, const float* __restrict__ bc1,
    const float* __restrict__ Wc2, const float* __restrict__ bc2,
    const float* __restrict__ Wr2, const float* __restrict__ br2,
    float* __restrict__ metric, float* __restrict__ mj,
    float* __restrict__ S, float* __restrict__ bc1s, float* __restrict__ Kc,
    int* __restrict__ cnt, float* __restrict__ Wp, float* __restrict__ c2,
    float* __restrict__ bmi_pre)
{
    __shared__ float sbuf[3392];
    const int role = blockIdx.x, t = threadIdx.x;

    if (role >= B) {
        // ---- Wp / c2 path: symmetrize one Wr2 row, contract with points ----
        const int u = role - B;                 // 0..255 = Wr2 row, 256 = br2
        float* row    = sbuf;                   // [32][33] = 1056
        float* rowsym = sbuf + 1056;            // [32][36] = 1152
        float* ps     = sbuf + 2208;            // [32][36] = 1152
        const float* src = (u < 256) ? (Wr2 + u * 1024) : br2;
        #pragma unroll
        for (int r = 0; r < 4; ++r) {
            const int d = t + 256 * r;
            row[(d >> 5) * 33 + (d & 31)] = src[d];
            ps[(d >> 5) * 36 + (d & 31)]  = points[d];
        }
        __syncthreads();
        #pragma unroll
        for (int r = 0; r < 4; ++r) {
            const int d = t + 256 * r, ii = d >> 5, jj = d & 31;
            rowsym[ii * 36 + jj] = 0.5f * (row[ii * 33 + jj] + row[jj * 33 + ii]);
        }
        __syncthreads();
        const int b = t >> 3, i0 = (t & 7) * 4;
        const float4* rs4 = (const float4*)rowsym;      // row stride 9 float4
        const float4* p4  = (const float4*)(ps + b * 36);
        float4 o; o.x = o.y = o.z = o.w = 0.f;
        #pragma unroll
        for (int m = 0; m < 8; ++m) {
            const float4 pv = p4[m];
            const float4 r0 = rs4[(i0 + 0) * 9 + m];
            const float4 r1 = rs4[(i0 + 1) * 9 + m];
            const float4 r2 = rs4[(i0 + 2) * 9 + m];
            const float4 r3 = rs4[(i0 + 3) * 9 + m];
            o.x = fmaf(pv.x, r0.x, fmaf(pv.y, r0.y, fmaf(pv.z, r0.z, fmaf(pv.w, r0.w, o.x))));
            o.y = fmaf(pv.x, r1.x, fmaf(pv.y, r1.y, fmaf(pv.z, r1.z, fmaf(pv.w, r1.w, o.y))));
            o.z = fmaf(pv.x, r2.x, fmaf(pv.y, r2.y, fmaf(pv.z, r2.z, fmaf(pv.w, r2.w, o.z))));
            o.w = fmaf(pv.x, r3.x, fmaf(pv.y, r3.y, fmaf(pv.z, r3.z, fmaf(pv.w, r3.w, o.w))));
        }
        if (u < 256) ((float4*)(Wp + u * 1024 + b * 32))[t & 7] = o;
        else         ((float4*)(c2 + b * 32))[t & 7] = o;
        return;
    }

    // ---- per-b prep path ----
    const int b = role;
    float* p     = sbuf;           // 32
    float* h     = sbuf + 32;      // 128
    float* comps = sbuf + 160;     // [32][33] = 1056
    float* msym  = sbuf + 1216;    // 1024
    if (t < M) p[t] = points[b * M + t];
    __syncthreads();
    if (t < H) {
        float acc = bm1[t];
        #pragma unroll
        for (int m = 0; m < M; ++m) acc = fmaf(p[m], Wm1[m * H + t], acc);
        h[t] = fmaxf(acc, 0.f);
    }
    __syncthreads();
    // comps: thread t owns 4 consecutive dims; b128 Wm2 loads, h broadcasts.
    {
        float4 acc = ((const float4*)bm2)[t];
        const float4* Wm2_4 = (const float4*)Wm2;     // row stride 256 float4
        const float4* h4 = (const float4*)h;
        #pragma unroll 2
        for (int u4 = 0; u4 < 32; ++u4) {
            const float4 hv = h4[u4];
            const float4 w0 = Wm2_4[(u4 * 4 + 0) * 256 + t];
            const float4 w1 = Wm2_4[(u4 * 4 + 1) * 256 + t];
            const float4 w2 = Wm2_4[(u4 * 4 + 2) * 256 + t];
            const float4 w3 = Wm2_4[(u4 * 4 + 3) * 256 + t];
            FMA4(acc, hv.x, w0); FMA4(acc, hv.y, w1);
            FMA4(acc, hv.z, w2); FMA4(acc, hv.w, w3);
        }
        const int row = t >> 3, col0 = (t & 7) * 4;
        comps[row * 33 + col0 + 0] = acc.x;
        comps[row * 33 + col0 + 1] = acc.y;
        comps[row * 33 + col0 + 2] = acc.z;
        comps[row * 33 + col0 + 3] = acc.w;
    }
    __syncthreads();
    {
        const int row = t >> 3, col0 = (t & 7) * 4;
        #pragma unroll
        for (int c = 0; c < 4; ++c) {
            const int d = 4 * t + c, ii = row, jj = col0 + c;
            float v = 0.5f * (comps[ii * 33 + jj] + comps[jj * 33 + ii]) + (ii == jj ? EPS : 0.f);
            metric[b * M * M + d] = v;
            msym[d] = v;
        }
    }
    S[b * 256 + t] = 0.f;
    if (t == 0) cnt[b] = 0;
    __syncthreads();
    // mj[b][x][t] and bmi_pre[b][x][t] in one pass (wreg = Wr1[64:96],
    // wreg2 = Wr1[32:64]); pbr = br1 + points@Wr1[0:32].
    float wreg[M], wreg2[M];
    #pragma unroll
    for (int m = 0; m < M; ++m) {
        wreg[m]  = Wr1[(64 + m) * 256 + t];
        wreg2[m] = Wr1[(32 + m) * 256 + t];
    }
    float pbr = br1[t];
    #pragma unroll
    for (int m = 0; m < M; ++m) pbr = fmaf(p[m], Wr1[m * 256 + t], pbr);
    const float4* msym4 = (const float4*)msym;   // broadcast reads
    for (int x = 0; x < M; ++x) {
        float acc = 0.f, acc2 = pbr;
        #pragma unroll
        for (int mq = 0; mq < 8; ++mq) {
            float4 mv = msym4[x * 8 + mq];
            acc  = fmaf(mv.x, wreg[4 * mq + 0], acc);
            acc  = fmaf(mv.y, wreg[4 * mq + 1], acc);
            acc  = fmaf(mv.z, wreg[4 * mq + 2], acc);
            acc  = fmaf(mv.w, wreg[4 * mq + 3], acc);
            acc2 = fmaf(mv.x, wreg2[4 * mq + 0], acc2);
            acc2 = fmaf(mv.y, wreg2[4 * mq + 1], acc2);
            acc2 = fmaf(mv.z, wreg2[4 * mq + 2], acc2);
            acc2 = fmaf(mv.w, wreg2[4 * mq + 3], acc2);
        }
        mj[(b * M + x) * 256 + t] = acc;
        bmi_pre[(b * M + x) * 256 + t] = acc2;
    }
    if (b == 0) {
        if (t < H) bc1s[t] = bc1[t] * TSCALE;
        if (t == 0) {
            float s = bc2[0];
            for (int u = 0; u < H; ++u) s += Wc2[u];
            Kc[0] = s;
        }
    }
}

// Kernel 2, grid 512: block (b, i-pair). __launch_bounds__(512, 2) gives the
// register allocator a 256-VGPR budget (2 waves/EU) — measurement shows we
// never co-reside >2 blocks/CU anyway, and the default allocation (32 VGPR,
// round 16) serialized the 4 chris tanh streams + 8 ricci accumulators.
__global__ __launch_bounds__(512, 2) void k_main(
    const float* __restrict__ points, const float* __restrict__ metric,
    const float* __restrict__ mj, const float* __restrict__ bmi_pre,
    const float* __restrict__ Wc1, const float* __restrict__ Wc2,
    const float* __restrict__ bc1s, const float* __restrict__ Kc,
    const float* __restrict__ Wr1, float* __restrict__ S,
    int* __restrict__ cnt,
    const float* __restrict__ Wp, const float* __restrict__ c2,
    const float* __restrict__ Wf1, const float* __restrict__ bf1,
    const float* __restrict__ Wf2, const float* __restrict__ bf2,
    const float* __restrict__ Wh1, const float* __restrict__ bh1,
    const float* __restrict__ Wh2, const float* __restrict__ bh2,
    float* __restrict__ out)
{
    const int blk = blockIdx.x;
    const int b = blk & 31, g = blk >> 5;      // same-b blocks share an XCD
    const int i0 = 2 * g, i1 = 2 * g + 1;
    const int t = threadIdx.x;
    const int w = t >> 6, l = t & 63;
    const int ph = l >> 5, k = l & 31;

    __shared__ float chlds[8 * 256];  // per-wave chris [i][k][slot] (8 KB)
    __shared__ float Slds[256];       // 1 KB
    __shared__ int finflag;

    // ---- early loads ----
    const float* mb = metric + b * 1024;
    const int j0 = 2 * w + ph, j1 = 16 + 2 * w + ph;
    const float gki0 = mb[i0 * M + k] * TSCALE;
    const float gki1 = mb[i1 * M + k] * TSCALE;
    const v2f gij0v = {mb[i0 * M + j0] * TSCALE, mb[i0 * M + j1] * TSCALE};
    const v2f gij1v = {mb[i1 * M + j0] * TSCALE, mb[i1 * M + j1] * TSCALE};
    const v2f gjkv  = {mb[j0 * M + k] * TSCALE, mb[j1 * M + k] * TSCALE};
    const v4f* mj4 = (const v4f*)(mj + b * M * 256);
    const int jb = w * 2;
    const v4f m0 = mj4[(jb + 0) * 64 + l];
    const v4f m1 = mj4[(jb + 1) * 64 + l];
    const v4f m2 = mj4[(jb + 16) * 64 + l];
    const v4f m3 = mj4[(jb + 17) * 64 + l];
    const v4f bmiv0 = ((const v4f*)(bmi_pre + (b * M + i0) * 256))[l];
    const v4f bmiv1 = ((const v4f*)(bmi_pre + (b * M + i1) * 256))[l];
    if (t < 256) Slds[t] = 0.f;

    // ---- christoffel: 2 i's x v2f = 4 independent tanh streams ----
    v2f accA = {0.f, 0.f}, accB = {0.f, 0.f};
    #pragma unroll 8
    for (int u = 0; u < H; ++u) {
        const float w1u = Wc1[u], w2u = Wc1[H + u], w3u = Wc1[2 * H + u];
        const float c2u = Wc2[u];
        const v2f base = fma2(gjkv, splat2(w2u), splat2(bc1s[u]));  // shared
        v2f pre0 = fma2(gij0v, splat2(w1u), fma2(splat2(gki0), splat2(w3u), base));
        v2f pre1 = fma2(gij1v, splat2(w1u), fma2(splat2(gki1), splat2(w3u), base));
        v2f e0 = {__builtin_amdgcn_exp2f(pre0.x), __builtin_amdgcn_exp2f(pre0.y)};
        v2f e1 = {__builtin_amdgcn_exp2f(pre1.x), __builtin_amdgcn_exp2f(pre1.y)};
        e0 += (v2f){1.f, 1.f};
        e1 += (v2f){1.f, 1.f};
        const v2f r0 = {__builtin_amdgcn_rcpf(e0.x), __builtin_amdgcn_rcpf(e0.y)};
        const v2f r1 = {__builtin_amdgcn_rcpf(e1.x), __builtin_amdgcn_rcpf(e1.y)};
        accA = fma2(r0, splat2(c2u), accA);
        accB = fma2(r1, splat2(c2u), accB);
    }
    const float KcV = Kc[0];
    // per-wave scratch, packed [i][k][slot] -> two broadcast b128 per k.
    float* chw = chlds + w * 256;
    chw[k * 4 + ph]           = fmaf(-2.f, accA.x, KcV);   // i0, j0-group
    chw[k * 4 + 2 + ph]       = fmaf(-2.f, accA.y, KcV);   // i0, j1-group
    chw[128 + k * 4 + ph]     = fmaf(-2.f, accB.x, KcV);   // i1, j0-group
    chw[128 + k * 4 + 2 + ph] = fmaf(-2.f, accB.y, KcV);   // i1, j1-group
    // wave-private: intra-wave lgkmcnt ordering suffices, no barrier.

    // ---- ricci layer-1: one weight load feeds 8 accumulators ----
    const v4f* wg = (const v4f*)(Wr1 + 96 * 256);
    const v4f* chA = (const v4f*)chw;          // i0 broadcasts
    const v4f* chB = chA + 32;                 // i1 broadcasts
    v4f a0 = m0 + bmiv0, a1 = m1 + bmiv0, a2 = m2 + bmiv0, a3 = m3 + bmiv0;
    v4f b0 = m0 + bmiv1, b1 = m1 + bmiv1, b2 = m2 + bmiv1, b3 = m3 + bmiv1;

    #define STEP(W, kk) { \
        const v4f sA = chA[kk]; const v4f sB = chB[kk]; \
        a0 = fma4(splat4(sA.x), W, a0); a1 = fma4(splat4(sA.y), W, a1); \
        a2 = fma4(splat4(sA.z), W, a2); a3 = fma4(splat4(sA.w), W, a3); \
        b0 = fma4(splat4(sB.x), W, b0); b1 = fma4(splat4(sB.y), W, b1); \
        b2 = fma4(splat4(sB.z), W, b2); b3 = fma4(splat4(sB.w), W, b3); }

    #pragma unroll
    for (int kc = 0; kc < 8; ++kc) {
        const int kb = kc * 4;
        const v4f w0 = wg[(kb + 0) * 64 + l];
        const v4f w1 = wg[(kb + 1) * 64 + l];
        const v4f w2 = wg[(kb + 2) * 64 + l];
        const v4f w3 = wg[(kb + 3) * 64 + l];
        STEP(w0, kb + 0) STEP(w1, kb + 1) STEP(w2, kb + 2) STEP(w3, kb + 3)
    }
    #undef STEP

    const v4f z4 = {0.f, 0.f, 0.f, 0.f};
    v4f rs = __builtin_elementwise_max(a0, z4) + __builtin_elementwise_max(a1, z4)
           + __builtin_elementwise_max(a2, z4) + __builtin_elementwise_max(a3, z4)
           + __builtin_elementwise_max(b0, z4) + __builtin_elementwise_max(b1, z4)
           + __builtin_elementwise_max(b2, z4) + __builtin_elementwise_max(b3, z4);
    atomicAdd(&Slds[4*l + 0], rs.x);
    atomicAdd(&Slds[4*l + 1], rs.y);
    atomicAdd(&Slds[4*l + 2], rs.z);
    atomicAdd(&Slds[4*l + 3], rs.w);
    __syncthreads();
    if (t < 256) atomicAdd(&S[b * 256 + t], Slds[t]);
    asm volatile("s_waitcnt vmcnt(0)" ::: "memory");  // S atomics done before cnt
    __syncthreads();
    if (t == 0) {
        int old = atomicAdd(&cnt[b], 1);
        finflag = (old == 15);
    }
    __syncthreads();
    if (!finflag) return;

    // ===== tiny epilogue (one block per b): ricci_dir via Wp, then MLPs =====
    float* fs   = chlds;          // 256
    float* rdp  = chlds + 256;    // 512
    float* pl   = chlds + 768;    // 32
    float* fin  = chlds + 800;    // 64
    float* hf   = chlds + 864;    // 128
    float* npos = Slds;           // 32
    float* hh   = Slds + 32;      // 128

    if (t < 256) fs[t] = atomicAdd(&S[b * 256 + t], 0.f) * (1.f / 1024.f);
    if (t < M) pl[t] = points[b * M + t];
    __syncthreads();
    {
        const int ii = t & 31, ch = t >> 5;   // 16 chunks x 16 u's
        float part = 0.f;
        #pragma unroll
        for (int uu = 0; uu < 16; ++uu) {
            const int u = ch * 16 + uu;
            part = fmaf(fs[u], Wp[u * 1024 + b * 32 + ii], part);
        }
        rdp[t] = part;
    }
    __syncthreads();
    if (t < M) {
        float a = c2[b * 32 + t];
        #pragma unroll
        for (int ch = 0; ch < 16; ++ch) a += rdp[ch * 32 + t];
        fin[t] = pl[t];
        fin[M + t] = a;
    }
    __syncthreads();
    if (t < H) {
        float acc = bf1[t];
        #pragma unroll
        for (int m = 0; m < 2 * M; ++m) acc = fmaf(fin[m], Wf1[m * H + t], acc);
        hf[t] = fmaxf(acc, 0.f);
    }
    __syncthreads();
    if (t < M) {
        float acc = bf2[t];
        #pragma unroll
        for (int u = 0; u < H; ++u) acc = fmaf(hf[u], Wf2[u * M + t], acc);
        npos[t] = pl[t] + acc;
    }
    __syncthreads();
    if (t < H) {
        float acc = bh1[t];
        #pragma unroll
        for (int m = 0; m < M; ++m) acc = fmaf(npos[m], Wh1[m * H + t], acc);
        hh[t] = tanhf(acc);
    }
    __syncthreads();
    if (t < 2 * M) {
        float acc = bh2[t];
        #pragma unroll
        for (int u = 0; u < H; ++u) acc = fmaf(hh[u], Wh2[u * (2 * M) + t], acc);
        out[b * (2 * M) + t] = acc;
    }
}

extern "C" void kernel_launch(void* const* d_in, const int* in_sizes, int n_in,
                              void* d_out, int out_size, void* d_ws, size_t ws_size,
                              hipStream_t stream)
{
    const float* points = (const float*)d_in[0];
    const float* Wm1 = (const float*)d_in[1];
    const float* bm1 = (const float*)d_in[2];
    const float* Wm2 = (const float*)d_in[3];
    const float* bm2 = (const float*)d_in[4];
    const float* Wc1 = (const float*)d_in[5];
    const float* bc1 = (const float*)d_in[6];
    const float* Wc2 = (const float*)d_in[7];
    const float* bc2 = (const float*)d_in[8];
    const float* Wr1 = (const float*)d_in[9];
    const float* br1 = (const float*)d_in[10];
    const float* Wr2 = (const float*)d_in[11];
    const float* br2 = (const float*)d_in[12];
    const float* Wf1 = (const float*)d_in[13];
    const float* bf1 = (const float*)d_in[14];
    const float* Wf2 = (const float*)d_in[15];
    const float* bf2 = (const float*)d_in[16];
    const float* Wh1 = (const float*)d_in[17];
    const float* bh1 = (const float*)d_in[18];
    const float* Wh2 = (const float*)d_in[19];
    const float* bh2 = (const float*)d_in[20];
    float* out = (float*)d_out;

    float* ws      = (float*)d_ws;
    float* metric  = ws;                    // 32768
    float* mj      = ws + 32768;            // 262144
    float* S       = ws + 294912;           // 8192
    float* bc1s    = ws + 303104;           // 128
    float* Kc      = ws + 303232;           // 1
    int*   cnt     = (int*)(ws + 303236);   // 32 ints
    float* Wp      = ws + 303268;           // 262144
    float* c2      = ws + 565412;           // 1024
    float* bmi_pre = ws + 566436;           // 262144

    k_prep<<<289, 256, 0, stream>>>(points, Wm1, bm1, Wm2, bm2, Wr1, br1, bc1,
                                    Wc2, bc2, Wr2, br2, metric, mj, S, bc1s,
                                    Kc, cnt, Wp, c2, bmi_pre);
    k_main<<<B * 16, 512, 0, stream>>>(points, metric, mj, bmi_pre, Wc1, Wc2,
                                       bc1s, Kc, Wr1, S, cnt,
                                       Wp, c2, Wf1, bf1, Wf2, bf2,
                                       Wh1, bh1, Wh2, bh2, out);
}